// Round 2
// baseline (1251.313 us; speedup 1.0000x reference)
//
#include <hip/hip_runtime.h>
#include <stdint.h>
#include <math.h>

typedef short bf16x8 __attribute__((ext_vector_type(8)));
typedef float f32x4 __attribute__((ext_vector_type(4)));

#if __has_builtin(__builtin_amdgcn_exp2f)
#define EXP2F(x) __builtin_amdgcn_exp2f(x)
#else
#define EXP2F(x) exp2f(x)
#endif

static constexpr int Bn   = 2;
static constexpr int Sn   = 2048;
static constexpr int NH   = 32;
static constexpr int NKV  = 8;
static constexpr int Dh   = 128;
static constexpr int En   = NH * Dh;     // 4096
static constexpr int KVEn = NKV * Dh;    // 1024
static constexpr int MT   = Bn * Sn;     // 4096 tokens
static constexpr int NT   = Sn / 64;     // 32 k-tiles

__device__ __forceinline__ unsigned short f2bf(float f) {
  unsigned int u = __float_as_uint(f);
  u += 0x7FFFu + ((u >> 16) & 1u);
  return (unsigned short)(u >> 16);
}
__device__ __forceinline__ float bf2f(unsigned short h) {
  return __uint_as_float(((unsigned int)h) << 16);
}

typedef __attribute__((address_space(1))) void* gas_t;
typedef __attribute__((address_space(3))) void* las_t;
// async global->LDS, 16B per lane; lds dest must be wave-base + lane*16 (linear)
__device__ __forceinline__ void gl_lds16(const void* g, void* l) {
  __builtin_amdgcn_global_load_lds((gas_t)(uintptr_t)g, (las_t)(uint32_t)(uintptr_t)l,
                                   16, 0, 0);
}

// ---------------- pre/post passes ----------------

__global__ void cast_bf16_kernel(const float* __restrict__ x,
                                 unsigned short* __restrict__ y, int n4) {
  int i = blockIdx.x * 256 + threadIdx.x;
  if (i >= n4) return;
  float4 v = ((const float4*)x)[i];
  ushort4 o;
  o.x = f2bf(v.x); o.y = f2bf(v.y); o.z = f2bf(v.z); o.w = f2bf(v.w);
  ((ushort4*)y)[i] = o;
}

// W [R][C] f32 -> WT [C][R] bf16 (tiled, coalesced both sides)
__global__ void tcast_kernel(const float* __restrict__ W,
                             unsigned short* __restrict__ WT, int R, int C) {
  __shared__ float t[32][33];
  int tx = threadIdx.x, ty = threadIdx.y;
  int c = blockIdx.x * 32 + tx, r = blockIdx.y * 32 + ty;
  t[ty][tx] = W[(size_t)r * C + c];
  __syncthreads();
  int ro = blockIdx.x * 32 + ty, co = blockIdx.y * 32 + tx;
  WT[(size_t)ro * R + co] = f2bf(t[tx][ty]);
}

__global__ void rope_table_kernel(float2* __restrict__ cs) {
  int i = blockIdx.x * 256 + threadIdx.x;   // i < Sn*64
  int s = i >> 6, d = i & 63;
  float inv = powf(10000.0f, -(float)d * (1.0f / 64.0f));
  float a = (float)s * inv;
  cs[i] = make_float2(cosf(a), sinf(a));
}

// in-place RoPE on [MT][heads*128]; pairs (d, d+64); optional scale folded in
__global__ void rope_kernel(unsigned short* __restrict__ q,
                            const float2* __restrict__ cs, int heads, float scl) {
  int row = blockIdx.x;
  int s = row & (Sn - 1);
  int hl = threadIdx.x >> 6, d = threadIdx.x & 63;
  int h = blockIdx.y * 4 + hl;
  size_t base = (size_t)row * (heads * Dh) + (size_t)h * Dh + d;
  float2 c = cs[s * 64 + d];
  float x0 = bf2f(q[base]), x1 = bf2f(q[base + 64]);
  q[base]      = f2bf((x0 * c.x - x1 * c.y) * scl);
  q[base + 64] = f2bf((x1 * c.x + x0 * c.y) * scl);
}

// Vl [MT][KVEn] -> Vt [B][KV][D][S]  (d-major so PV B-frags are k-contiguous)
__global__ void vtrans_kernel(const unsigned short* __restrict__ Vl,
                              unsigned short* __restrict__ Vt) {
  __shared__ unsigned short t[32][33];
  int bk = blockIdx.z;                 // b*NKV+kv
  int b = bk >> 3, kv = bk & 7;
  int d = blockIdx.x * 32 + threadIdx.x;
  int s = blockIdx.y * 32 + threadIdx.y;
  t[threadIdx.y][threadIdx.x] = Vl[((size_t)(b * Sn + s)) * KVEn + kv * Dh + d];
  __syncthreads();
  int dd = blockIdx.x * 32 + threadIdx.y;
  int so = blockIdx.y * 32 + threadIdx.x;
  Vt[((size_t)bk * Dh + dd) * Sn + so] = t[threadIdx.x][threadIdx.y];
}

// ---------------- GEMM (m97 structure): A[M,K] bf16, BT[N,K] bf16 -> C[M,N] ----------------

__global__ __launch_bounds__(256) void gemm_kernel(
    const unsigned short* __restrict__ A, const unsigned short* __restrict__ BT,
    void* __restrict__ Cout, int M, int N, int K, int out_f32) {
  __shared__ unsigned short As[128 * 32];
  __shared__ unsigned short Bs[128 * 32];
  const int tid = threadIdx.x;
  const int lane = tid & 63, wave = tid >> 6;
  const int r15 = lane & 15, kg = lane >> 4;
  const int m0 = blockIdx.y * 128, n0 = blockIdx.x * 128;
  const int wr = (wave >> 1) * 64, wc = (wave & 1) * 64;
  const char* Ab = (const char*)A;
  const char* Bb = (const char*)BT;

  f32x4 acc[4][4] = {};

  for (int k0 = 0; k0 < K; k0 += 32) {
    {
      int f0 = tid * 16;            // [0,4096)
      int f1 = f0 + 4096;           // [4096,8192)
      int r0 = f0 >> 6, o0 = f0 & 63;
      int r1 = f1 >> 6, o1 = f1 & 63;
      gl_lds16(Ab + ((size_t)(m0 + r0) * K + k0) * 2 + o0, (char*)As + f0);
      gl_lds16(Ab + ((size_t)(m0 + r1) * K + k0) * 2 + o1, (char*)As + f1);
      gl_lds16(Bb + ((size_t)(n0 + r0) * K + k0) * 2 + o0, (char*)Bs + f0);
      gl_lds16(Bb + ((size_t)(n0 + r1) * K + k0) * 2 + o1, (char*)Bs + f1);
    }
    __syncthreads();
    bf16x8 a[4], b[4];
#pragma unroll
    for (int i = 0; i < 4; ++i)
      a[i] = *(const bf16x8*)&As[(wr + i * 16 + r15) * 32 + kg * 8];
#pragma unroll
    for (int i = 0; i < 4; ++i)
      b[i] = *(const bf16x8*)&Bs[(wc + i * 16 + r15) * 32 + kg * 8];
#pragma unroll
    for (int i = 0; i < 4; ++i)
#pragma unroll
      for (int j = 0; j < 4; ++j)
        acc[i][j] = __builtin_amdgcn_mfma_f32_16x16x32_bf16(a[i], b[j], acc[i][j], 0, 0, 0);
    __syncthreads();
  }

#pragma unroll
  for (int i = 0; i < 4; ++i)
#pragma unroll
    for (int j = 0; j < 4; ++j)
#pragma unroll
      for (int t = 0; t < 4; ++t) {
        int row = m0 + wr + i * 16 + kg * 4 + t;   // C/D: row=(l>>4)*4+reg
        int col = n0 + wc + j * 16 + r15;          //      col=l&15
        if (out_f32)
          ((float*)Cout)[(size_t)row * N + col] = acc[i][j][t];
        else
          ((unsigned short*)Cout)[(size_t)row * N + col] = f2bf(acc[i][j][t]);
      }
}

// ---------------- flash attention (causal, GQA, paired q-tiles) ----------------
// Each block handles q-tiles jA and NT-1-jA (uniform 33 k-tiles of work).
// K/V staged once per k-tile, shared by both q-tiles. Double-buffered with
// prefetch-before-compute (T3 minimal 2-phase). Q pre-scaled by
// (1/sqrt(D))*log2(e); K raw.

// mask + online-softmax update + P write (one q-tile). PV done by caller so
// V-fragment reads are shared between the paired q-tiles.
__device__ __forceinline__ void sm_update(f32x4 sc[4], f32x4 o[8],
                                          float mrow[4], float lrow[4],
                                          bool diag, int wq16, int r15, int kg,
                                          char* Pw) {
  if (diag) {
#pragma unroll
    for (int kf = 0; kf < 4; ++kf) {
      int kvg = kf * 16 + r15;
#pragma unroll
      for (int t = 0; t < 4; ++t)
        if (kvg > wq16 + kg * 4 + t) sc[kf][t] = -1e30f;
    }
  }
  float mx[4], sm[4];
#pragma unroll
  for (int t = 0; t < 4; ++t) {
    float v = fmaxf(fmaxf(sc[0][t], sc[1][t]), fmaxf(sc[2][t], sc[3][t]));
#pragma unroll
    for (int off = 1; off < 16; off <<= 1) v = fmaxf(v, __shfl_xor(v, off, 16));
    mx[t] = fmaxf(mrow[t], v);
    sm[t] = EXP2F(mrow[t] - mx[t]);
    mrow[t] = mx[t];
  }
#pragma unroll
  for (int kf = 0; kf < 4; ++kf)
#pragma unroll
    for (int t = 0; t < 4; ++t) sc[kf][t] = EXP2F(sc[kf][t] - mx[t]);
#pragma unroll
  for (int t = 0; t < 4; ++t) {
    float v = sc[0][t] + sc[1][t] + sc[2][t] + sc[3][t];
#pragma unroll
    for (int off = 1; off < 16; off <<= 1) v += __shfl_xor(v, off, 16);
    lrow[t] = lrow[t] * sm[t] + v;
  }
#pragma unroll
  for (int nf = 0; nf < 8; ++nf)
#pragma unroll
    for (int t = 0; t < 4; ++t) o[nf][t] *= sm[t];
  // P (C-layout) -> per-wave LDS (A-layout source), swizzled
#pragma unroll
  for (int kf = 0; kf < 4; ++kf)
#pragma unroll
    for (int t = 0; t < 4; ++t) {
      int r = kg * 4 + t, c = kf * 16 + r15;
      *(unsigned short*)(Pw + r * 128 + ((c * 2) ^ ((r & 7) << 4))) = f2bf(sc[kf][t]);
    }
}

__global__ __launch_bounds__(256) void attn_kernel(
    const unsigned short* __restrict__ Q, const unsigned short* __restrict__ Kl,
    const unsigned short* __restrict__ Vt, unsigned short* __restrict__ AO) {
  __shared__ unsigned short Ks[2][64 * 128];   // [buf][kv][d], rows XOR-swizzled
  __shared__ unsigned short Vs[2][128 * 64];   // [buf][d][kv], rows XOR-swizzled
  __shared__ unsigned short Ps[4][2][16 * 64]; // per-wave P (A,B), swizzled
  const int tid = threadIdx.x, lane = tid & 63, wave = tid >> 6;
  const int jA = blockIdx.x, h = blockIdx.y, b = blockIdx.z;
  const int qtA = jA, qtB = (NT - 1) - jA;     // qtA < qtB always (jA < NT/2)
  const int kvh = h >> 2;                      // G = 4
  const int r15 = lane & 15, kg = lane >> 4;

  bf16x8 qfA[4], qfB[4];
#pragma unroll
  for (int db = 0; db < 4; ++db) {
    qfA[db] = *(const bf16x8*)&Q[((size_t)(b * Sn + qtA * 64 + wave * 16 + r15)) * En +
                                 h * Dh + db * 32 + kg * 8];
    qfB[db] = *(const bf16x8*)&Q[((size_t)(b * Sn + qtB * 64 + wave * 16 + r15)) * En +
                                 h * Dh + db * 32 + kg * 8];
  }

  f32x4 oA[8] = {}, oB[8] = {};
  float mA[4] = {-1e30f, -1e30f, -1e30f, -1e30f}, lA[4] = {0.f, 0.f, 0.f, 0.f};
  float mB[4] = {-1e30f, -1e30f, -1e30f, -1e30f}, lB[4] = {0.f, 0.f, 0.f, 0.f};

  const char* Kbase = (const char*)Kl + ((size_t)b * Sn) * (KVEn * 2) + kvh * 256;
  const char* Vbase = (const char*)Vt + ((size_t)(b * NKV + kvh) * Dh) * (Sn * 2);

  auto stage = [&](int kt, int bi) {
#pragma unroll
    for (int c = 0; c < 4; ++c) {
      int f = (c * 256 + tid) * 16;
      int row = f >> 8, cb = f & 255;
      gl_lds16(Kbase + (size_t)(kt * 64 + row) * (KVEn * 2) + (cb ^ ((row & 7) << 4)),
               (char*)Ks[bi] + f);
    }
#pragma unroll
    for (int c = 0; c < 4; ++c) {
      int f = (c * 256 + tid) * 16;
      int row = f >> 7, cb = f & 127;
      gl_lds16(Vbase + (size_t)row * (Sn * 2) + kt * 128 + (cb ^ ((row & 7) << 4)),
               (char*)Vs[bi] + f);
    }
  };

  stage(0, 0);
  __syncthreads();

  for (int kt = 0; kt <= qtB; ++kt) {
    const int cur = kt & 1;
    if (kt < qtB) stage(kt + 1, cur ^ 1);     // prefetch overlaps this tile's compute
    const bool doA = (kt <= qtA);
    const char* Kc = (const char*)Ks[cur];
    const char* Vc = (const char*)Vs[cur];

    // QK^T — K-fragment reads shared between paired q-tiles
    f32x4 scA[4] = {}, scB[4] = {};
    __builtin_amdgcn_s_setprio(1);
#pragma unroll
    for (int db = 0; db < 4; ++db) {
#pragma unroll
      for (int kf = 0; kf < 4; ++kf) {
        int krow = kf * 16 + r15;
        int cb = (db * 32 + kg * 8) * 2;
        bf16x8 kb = *(const bf16x8*)(Kc + krow * 256 + (cb ^ ((krow & 7) << 4)));
        scB[kf] = __builtin_amdgcn_mfma_f32_16x16x32_bf16(qfB[db], kb, scB[kf], 0, 0, 0);
        if (doA)
          scA[kf] = __builtin_amdgcn_mfma_f32_16x16x32_bf16(qfA[db], kb, scA[kf], 0, 0, 0);
      }
    }
    __builtin_amdgcn_s_setprio(0);

    char* PwA = (char*)Ps[wave][0];
    char* PwB = (char*)Ps[wave][1];
    sm_update(scB, oB, mB, lB, kt == qtB, wave * 16, r15, kg, PwB);
    if (doA) sm_update(scA, oA, mA, lA, kt == qtA, wave * 16, r15, kg, PwA);

    // PV — V-fragment reads shared between paired q-tiles
    __builtin_amdgcn_s_setprio(1);
#pragma unroll
    for (int ks = 0; ks < 2; ++ks) {
      bf16x8 paB = *(const bf16x8*)(PwB + r15 * 128 + ((kg * 16 + ks * 64) ^ ((r15 & 7) << 4)));
      bf16x8 paA = *(const bf16x8*)(PwA + r15 * 128 + ((kg * 16 + ks * 64) ^ ((r15 & 7) << 4)));
#pragma unroll
      for (int nf = 0; nf < 8; ++nf) {
        int vrow = nf * 16 + r15;
        int cb = (ks * 32 + kg * 8) * 2;
        bf16x8 vb = *(const bf16x8*)(Vc + vrow * 128 + (cb ^ ((vrow & 7) << 4)));
        oB[nf] = __builtin_amdgcn_mfma_f32_16x16x32_bf16(paB, vb, oB[nf], 0, 0, 0);
        if (doA)
          oA[nf] = __builtin_amdgcn_mfma_f32_16x16x32_bf16(paA, vb, oA[nf], 0, 0, 0);
      }
    }
    __builtin_amdgcn_s_setprio(0);
    __syncthreads();
  }

  float rA[4], rB[4];
#pragma unroll
  for (int t = 0; t < 4; ++t) { rA[t] = 1.0f / lA[t]; rB[t] = 1.0f / lB[t]; }
#pragma unroll
  for (int nf = 0; nf < 8; ++nf)
#pragma unroll
    for (int t = 0; t < 4; ++t) {
      int sA = qtA * 64 + wave * 16 + kg * 4 + t;
      int sB = qtB * 64 + wave * 16 + kg * 4 + t;
      AO[((size_t)(b * Sn + sA)) * En + h * Dh + nf * 16 + r15] = f2bf(oA[nf][t] * rA[t]);
      AO[((size_t)(b * Sn + sB)) * En + h * Dh + nf * 16 + r15] = f2bf(oB[nf][t] * rB[t]);
    }
}

// ---------------- launch ----------------

extern "C" void kernel_launch(void* const* d_in, const int* in_sizes, int n_in,
                              void* d_out, int out_size, void* d_ws, size_t ws_size,
                              hipStream_t stream) {
  const float* x  = (const float*)d_in[0];
  const float* Wq = (const float*)d_in[1];
  const float* Wk = (const float*)d_in[2];
  const float* Wv = (const float*)d_in[3];
  const float* Wo = (const float*)d_in[4];

  char* ws = (char*)d_ws;
  size_t off = 0;
  auto alloc = [&](size_t bytes) -> char* {
    char* p = ws + off;
    off += (bytes + 255) & ~(size_t)255;
    return p;
  };
  unsigned short* xb  = (unsigned short*)alloc((size_t)MT * En * 2);
  unsigned short* WqT = (unsigned short*)alloc((size_t)En * En * 2);
  unsigned short* WkT = (unsigned short*)alloc((size_t)KVEn * En * 2);
  unsigned short* WvT = (unsigned short*)alloc((size_t)KVEn * En * 2);
  unsigned short* WoT = (unsigned short*)alloc((size_t)En * En * 2);
  unsigned short* Ql  = (unsigned short*)alloc((size_t)MT * En * 2);
  unsigned short* Kl  = (unsigned short*)alloc((size_t)MT * KVEn * 2);
  unsigned short* Vl  = (unsigned short*)alloc((size_t)MT * KVEn * 2);
  unsigned short* Vt  = (unsigned short*)alloc((size_t)MT * KVEn * 2);
  float2* cs          = (float2*)alloc((size_t)Sn * 64 * sizeof(float2));
  unsigned short* AO  = xb;   // alias: xb dead after the V projection

  cast_bf16_kernel<<<MT * (En / 4) / 256, 256, 0, stream>>>(x, xb, MT * En / 4);
  tcast_kernel<<<dim3(En / 32, En / 32), dim3(32, 32), 0, stream>>>(Wq, WqT, En, En);
  tcast_kernel<<<dim3(KVEn / 32, En / 32), dim3(32, 32), 0, stream>>>(Wk, WkT, En, KVEn);
  tcast_kernel<<<dim3(KVEn / 32, En / 32), dim3(32, 32), 0, stream>>>(Wv, WvT, En, KVEn);
  tcast_kernel<<<dim3(En / 32, En / 32), dim3(32, 32), 0, stream>>>(Wo, WoT, En, En);
  rope_table_kernel<<<Sn * 64 / 256, 256, 0, stream>>>(cs);

  gemm_kernel<<<dim3(En / 128, MT / 128), 256, 0, stream>>>(xb, WqT, Ql, MT, En, En, 0);
  gemm_kernel<<<dim3(KVEn / 128, MT / 128), 256, 0, stream>>>(xb, WkT, Kl, MT, KVEn, En, 0);
  gemm_kernel<<<dim3(KVEn / 128, MT / 128), 256, 0, stream>>>(xb, WvT, Vl, MT, KVEn, En, 0);

  const float scl = 0.08838834764831845f * 1.4426950408889634f; // (1/sqrt(128))*log2(e)
  rope_kernel<<<dim3(MT, NH / 4), 256, 0, stream>>>(Ql, cs, NH, scl);
  rope_kernel<<<dim3(MT, NKV / 4), 256, 0, stream>>>(Kl, cs, NKV, 1.0f);
  vtrans_kernel<<<dim3(Dh / 32, Sn / 32, Bn * NKV), dim3(32, 32), 0, stream>>>(Vl, Vt);

  attn_kernel<<<dim3(NT / 2, NH, Bn), 256, 0, stream>>>(Ql, Kl, Vt, AO);

  gemm_kernel<<<dim3(En / 128, MT / 128), 256, 0, stream>>>(AO, WoT, d_out, MT, En, En, 1);
}

// Round 3
// 874.486 us; speedup vs baseline: 1.4309x; 1.4309x over previous
//
#include <hip/hip_runtime.h>
#include <stdint.h>
#include <math.h>

typedef short bf16x8 __attribute__((ext_vector_type(8)));
typedef float f32x4 __attribute__((ext_vector_type(4)));

#if __has_builtin(__builtin_amdgcn_exp2f)
#define EXP2F(x) __builtin_amdgcn_exp2f(x)
#else
#define EXP2F(x) exp2f(x)
#endif

static constexpr int Bn   = 2;
static constexpr int Sn   = 2048;
static constexpr int NH   = 32;
static constexpr int NKV  = 8;
static constexpr int Dh   = 128;
static constexpr int En   = NH * Dh;     // 4096
static constexpr int KVEn = NKV * Dh;    // 1024
static constexpr int MT   = Bn * Sn;     // 4096 tokens
static constexpr int QT   = Sn / 128;    // 16 q-tiles (128 rows each)

__device__ __forceinline__ unsigned short f2bf(float f) {
  unsigned int u = __float_as_uint(f);
  u += 0x7FFFu + ((u >> 16) & 1u);
  return (unsigned short)(u >> 16);
}
__device__ __forceinline__ float bf2f(unsigned short h) {
  return __uint_as_float(((unsigned int)h) << 16);
}

typedef __attribute__((address_space(1))) void* gas_t;
typedef __attribute__((address_space(3))) void* las_t;
// async global->LDS, 16B per lane; lds dest must be wave-base + lane*16 (linear)
__device__ __forceinline__ void gl_lds16(const void* g, void* l) {
  __builtin_amdgcn_global_load_lds((gas_t)(uintptr_t)g, (las_t)(uint32_t)(uintptr_t)l,
                                   16, 0, 0);
}

// ---------------- pre/post passes ----------------

__global__ void cast_bf16_kernel(const float* __restrict__ x,
                                 unsigned short* __restrict__ y, int n4) {
  int i = blockIdx.x * 256 + threadIdx.x;
  if (i >= n4) return;
  float4 v = ((const float4*)x)[i];
  ushort4 o;
  o.x = f2bf(v.x); o.y = f2bf(v.y); o.z = f2bf(v.z); o.w = f2bf(v.w);
  ((ushort4*)y)[i] = o;
}

// W [R][C] f32 -> WT [C][R] bf16 (tiled, coalesced both sides)
__global__ void tcast_kernel(const float* __restrict__ W,
                             unsigned short* __restrict__ WT, int R, int C) {
  __shared__ float t[32][33];
  int tx = threadIdx.x, ty = threadIdx.y;
  int c = blockIdx.x * 32 + tx, r = blockIdx.y * 32 + ty;
  t[ty][tx] = W[(size_t)r * C + c];
  __syncthreads();
  int ro = blockIdx.x * 32 + ty, co = blockIdx.y * 32 + tx;
  WT[(size_t)ro * R + co] = f2bf(t[tx][ty]);
}

__global__ void rope_table_kernel(float2* __restrict__ cs) {
  int i = blockIdx.x * 256 + threadIdx.x;   // i < Sn*64
  int s = i >> 6, d = i & 63;
  float inv = powf(10000.0f, -(float)d * (1.0f / 64.0f));
  float a = (float)s * inv;
  cs[i] = make_float2(cosf(a), sinf(a));
}

// in-place RoPE on [MT][heads*128]; pairs (d, d+64); optional scale folded in
__global__ void rope_kernel(unsigned short* __restrict__ q,
                            const float2* __restrict__ cs, int heads, float scl) {
  int row = blockIdx.x;
  int s = row & (Sn - 1);
  int hl = threadIdx.x >> 6, d = threadIdx.x & 63;
  int h = blockIdx.y * 4 + hl;
  size_t base = (size_t)row * (heads * Dh) + (size_t)h * Dh + d;
  float2 c = cs[s * 64 + d];
  float x0 = bf2f(q[base]), x1 = bf2f(q[base + 64]);
  q[base]      = f2bf((x0 * c.x - x1 * c.y) * scl);
  q[base + 64] = f2bf((x1 * c.x + x0 * c.y) * scl);
}

// Vl [MT][KVEn] -> Vt [B][KV][D][S]  (d-major so PV B-frags are k-contiguous)
__global__ void vtrans_kernel(const unsigned short* __restrict__ Vl,
                              unsigned short* __restrict__ Vt) {
  __shared__ unsigned short t[32][33];
  int bk = blockIdx.z;                 // b*NKV+kv
  int b = bk >> 3, kv = bk & 7;
  int d = blockIdx.x * 32 + threadIdx.x;
  int s = blockIdx.y * 32 + threadIdx.y;
  t[threadIdx.y][threadIdx.x] = Vl[((size_t)(b * Sn + s)) * KVEn + kv * Dh + d];
  __syncthreads();
  int dd = blockIdx.x * 32 + threadIdx.y;
  int so = blockIdx.y * 32 + threadIdx.x;
  Vt[((size_t)bk * Dh + dd) * Sn + so] = t[threadIdx.x][threadIdx.y];
}

// ---------------- GEMM (m97 structure): A[M,K] bf16, BT[N,K] bf16 -> C[M,N] ----------------

__global__ __launch_bounds__(256) void gemm_kernel(
    const unsigned short* __restrict__ A, const unsigned short* __restrict__ BT,
    void* __restrict__ Cout, int M, int N, int K, int out_f32) {
  __shared__ unsigned short As[128 * 32];
  __shared__ unsigned short Bs[128 * 32];
  const int tid = threadIdx.x;
  const int lane = tid & 63, wave = tid >> 6;
  const int r15 = lane & 15, kg = lane >> 4;
  const int m0 = blockIdx.y * 128, n0 = blockIdx.x * 128;
  const int wr = (wave >> 1) * 64, wc = (wave & 1) * 64;
  const char* Ab = (const char*)A;
  const char* Bb = (const char*)BT;

  f32x4 acc[4][4] = {};

  for (int k0 = 0; k0 < K; k0 += 32) {
    {
      int f0 = tid * 16;            // [0,4096)
      int f1 = f0 + 4096;           // [4096,8192)
      int r0 = f0 >> 6, o0 = f0 & 63;
      int r1 = f1 >> 6, o1 = f1 & 63;
      gl_lds16(Ab + ((size_t)(m0 + r0) * K + k0) * 2 + o0, (char*)As + f0);
      gl_lds16(Ab + ((size_t)(m0 + r1) * K + k0) * 2 + o1, (char*)As + f1);
      gl_lds16(Bb + ((size_t)(n0 + r0) * K + k0) * 2 + o0, (char*)Bs + f0);
      gl_lds16(Bb + ((size_t)(n0 + r1) * K + k0) * 2 + o1, (char*)Bs + f1);
    }
    __syncthreads();
    bf16x8 a[4], b[4];
#pragma unroll
    for (int i = 0; i < 4; ++i)
      a[i] = *(const bf16x8*)&As[(wr + i * 16 + r15) * 32 + kg * 8];
#pragma unroll
    for (int i = 0; i < 4; ++i)
      b[i] = *(const bf16x8*)&Bs[(wc + i * 16 + r15) * 32 + kg * 8];
#pragma unroll
    for (int i = 0; i < 4; ++i)
#pragma unroll
      for (int j = 0; j < 4; ++j)
        acc[i][j] = __builtin_amdgcn_mfma_f32_16x16x32_bf16(a[i], b[j], acc[i][j], 0, 0, 0);
    __syncthreads();
  }

#pragma unroll
  for (int i = 0; i < 4; ++i)
#pragma unroll
    for (int j = 0; j < 4; ++j)
#pragma unroll
      for (int t = 0; t < 4; ++t) {
        int row = m0 + wr + i * 16 + kg * 4 + t;   // C/D: row=(l>>4)*4+reg
        int col = n0 + wc + j * 16 + r15;          //      col=l&15
        if (out_f32)
          ((float*)Cout)[(size_t)row * N + col] = acc[i][j][t];
        else
          ((unsigned short*)Cout)[(size_t)row * N + col] = f2bf(acc[i][j][t]);
      }
}

// ---------------- flash attention (causal, GQA) ----------------
// 512 threads = 8 waves x 16 q-rows => 128 q-rows/block sharing one staged
// K/V tile (KVBLK=64). Double-buffered prefetch, one barrier per k-tile.
// Longest blocks dispatched first (qt reversed). Q pre-scaled by
// (1/sqrt(D))*log2(e); K raw.

__device__ __forceinline__ void sm_update(f32x4 sc[4], f32x4 o[8],
                                          float mrow[4], float lrow[4],
                                          bool diag, int qrow0, int kt,
                                          int r15, int kg, char* Pw) {
  if (diag) {
#pragma unroll
    for (int kf = 0; kf < 4; ++kf) {
      int kvg = kt * 64 + kf * 16 + r15;
#pragma unroll
      for (int t = 0; t < 4; ++t)
        if (kvg > qrow0 + kg * 4 + t) sc[kf][t] = -1e30f;
    }
  }
  float mx[4], sm[4];
#pragma unroll
  for (int t = 0; t < 4; ++t) {
    float v = fmaxf(fmaxf(sc[0][t], sc[1][t]), fmaxf(sc[2][t], sc[3][t]));
#pragma unroll
    for (int off = 1; off < 16; off <<= 1) v = fmaxf(v, __shfl_xor(v, off, 16));
    mx[t] = fmaxf(mrow[t], v);
    sm[t] = EXP2F(mrow[t] - mx[t]);
    mrow[t] = mx[t];
  }
#pragma unroll
  for (int kf = 0; kf < 4; ++kf)
#pragma unroll
    for (int t = 0; t < 4; ++t) sc[kf][t] = EXP2F(sc[kf][t] - mx[t]);
#pragma unroll
  for (int t = 0; t < 4; ++t) {
    float v = sc[0][t] + sc[1][t] + sc[2][t] + sc[3][t];
#pragma unroll
    for (int off = 1; off < 16; off <<= 1) v += __shfl_xor(v, off, 16);
    lrow[t] = lrow[t] * sm[t] + v;
  }
#pragma unroll
  for (int nf = 0; nf < 8; ++nf)
#pragma unroll
    for (int t = 0; t < 4; ++t) o[nf][t] *= sm[t];
  // P (C-layout) -> per-wave LDS (A-layout source), swizzled
#pragma unroll
  for (int kf = 0; kf < 4; ++kf)
#pragma unroll
    for (int t = 0; t < 4; ++t) {
      int r = kg * 4 + t, c = kf * 16 + r15;
      *(unsigned short*)(Pw + r * 128 + ((c * 2) ^ ((r & 7) << 4))) = f2bf(sc[kf][t]);
    }
}

__global__ __launch_bounds__(512, 4) void attn_kernel(
    const unsigned short* __restrict__ Q, const unsigned short* __restrict__ Kl,
    const unsigned short* __restrict__ Vt, unsigned short* __restrict__ AO) {
  __shared__ unsigned short Ks[2][64 * 128];   // [buf][kv][d], rows XOR-swizzled
  __shared__ unsigned short Vs[2][128 * 64];   // [buf][d][kv], rows XOR-swizzled
  __shared__ unsigned short Ps[8][16 * 64];    // per-wave P, swizzled
  const int tid = threadIdx.x, lane = tid & 63, wave = tid >> 6;
  const int h = blockIdx.x, b = blockIdx.z;
  const int qt = (QT - 1) - blockIdx.y;        // longest-first dispatch
  const int kvh = h >> 2;                      // G = 4
  const int r15 = lane & 15, kg = lane >> 4;
  const int qrow0 = qt * 128 + wave * 16;
  const int kmax = 2 * qt + 2;

  bf16x8 qf[4];
#pragma unroll
  for (int db = 0; db < 4; ++db)
    qf[db] = *(const bf16x8*)&Q[((size_t)(b * Sn + qrow0 + r15)) * En +
                                h * Dh + db * 32 + kg * 8];

  f32x4 o[8] = {};
  float mrow[4] = {-1e30f, -1e30f, -1e30f, -1e30f};
  float lrow[4] = {0.f, 0.f, 0.f, 0.f};

  const char* Kbase = (const char*)Kl + ((size_t)b * Sn) * (KVEn * 2) + kvh * 256;
  const char* Vbase = (const char*)Vt + ((size_t)(b * NKV + kvh) * Dh) * (Sn * 2);

  auto stage = [&](int kt, int bi) {
#pragma unroll
    for (int c = 0; c < 2; ++c) {
      int f = (c * 512 + tid) * 16;
      int row = f >> 8, cb = f & 255;
      gl_lds16(Kbase + (size_t)(kt * 64 + row) * (KVEn * 2) + (cb ^ ((row & 7) << 4)),
               (char*)Ks[bi] + f);
    }
#pragma unroll
    for (int c = 0; c < 2; ++c) {
      int f = (c * 512 + tid) * 16;
      int row = f >> 7, cb = f & 127;
      gl_lds16(Vbase + (size_t)row * (Sn * 2) + kt * 128 + (cb ^ ((row & 7) << 4)),
               (char*)Vs[bi] + f);
    }
  };

  stage(0, 0);
  __syncthreads();

  for (int kt = 0; kt < kmax; ++kt) {
    const int cur = kt & 1;
    if (kt + 1 < kmax) stage(kt + 1, cur ^ 1);   // prefetch overlaps compute
    // skip tiles fully above the diagonal for this wave's strip (wave-uniform)
    if (kt * 64 <= qrow0 + 15) {
      const char* Kc = (const char*)Ks[cur];
      const char* Vc = (const char*)Vs[cur];
      f32x4 sc[4] = {};
      __builtin_amdgcn_s_setprio(1);
#pragma unroll
      for (int db = 0; db < 4; ++db) {
#pragma unroll
        for (int kf = 0; kf < 4; ++kf) {
          int krow = kf * 16 + r15;
          int cb = (db * 32 + kg * 8) * 2;
          bf16x8 kb = *(const bf16x8*)(Kc + krow * 256 + (cb ^ ((krow & 7) << 4)));
          sc[kf] = __builtin_amdgcn_mfma_f32_16x16x32_bf16(qf[db], kb, sc[kf], 0, 0, 0);
        }
      }
      __builtin_amdgcn_s_setprio(0);

      char* Pw = (char*)Ps[wave];
      bool diag = (kt * 64 + 63) > qrow0;        // tile touches the diagonal
      sm_update(sc, o, mrow, lrow, diag, qrow0, kt, r15, kg, Pw);

      __builtin_amdgcn_s_setprio(1);
#pragma unroll
      for (int ks = 0; ks < 2; ++ks) {
        bf16x8 pa = *(const bf16x8*)(Pw + r15 * 128 + ((kg * 16 + ks * 64) ^ ((r15 & 7) << 4)));
#pragma unroll
        for (int nf = 0; nf < 8; ++nf) {
          int vrow = nf * 16 + r15;
          int cb = (ks * 32 + kg * 8) * 2;
          bf16x8 vb = *(const bf16x8*)(Vc + vrow * 128 + (cb ^ ((vrow & 7) << 4)));
          o[nf] = __builtin_amdgcn_mfma_f32_16x16x32_bf16(pa, vb, o[nf], 0, 0, 0);
        }
      }
      __builtin_amdgcn_s_setprio(0);
    }
    __syncthreads();
  }

  float rinv[4];
#pragma unroll
  for (int t = 0; t < 4; ++t) rinv[t] = 1.0f / lrow[t];
#pragma unroll
  for (int nf = 0; nf < 8; ++nf)
#pragma unroll
    for (int t = 0; t < 4; ++t) {
      int srow = qrow0 + kg * 4 + t;
      AO[((size_t)(b * Sn + srow)) * En + h * Dh + nf * 16 + r15] = f2bf(o[nf][t] * rinv[t]);
    }
}

// ---------------- launch ----------------

extern "C" void kernel_launch(void* const* d_in, const int* in_sizes, int n_in,
                              void* d_out, int out_size, void* d_ws, size_t ws_size,
                              hipStream_t stream) {
  const float* x  = (const float*)d_in[0];
  const float* Wq = (const float*)d_in[1];
  const float* Wk = (const float*)d_in[2];
  const float* Wv = (const float*)d_in[3];
  const float* Wo = (const float*)d_in[4];

  char* ws = (char*)d_ws;
  size_t off = 0;
  auto alloc = [&](size_t bytes) -> char* {
    char* p = ws + off;
    off += (bytes + 255) & ~(size_t)255;
    return p;
  };
  unsigned short* xb  = (unsigned short*)alloc((size_t)MT * En * 2);
  unsigned short* WqT = (unsigned short*)alloc((size_t)En * En * 2);
  unsigned short* WkT = (unsigned short*)alloc((size_t)KVEn * En * 2);
  unsigned short* WvT = (unsigned short*)alloc((size_t)KVEn * En * 2);
  unsigned short* WoT = (unsigned short*)alloc((size_t)En * En * 2);
  unsigned short* Ql  = (unsigned short*)alloc((size_t)MT * En * 2);
  unsigned short* Kl  = (unsigned short*)alloc((size_t)MT * KVEn * 2);
  unsigned short* Vl  = (unsigned short*)alloc((size_t)MT * KVEn * 2);
  unsigned short* Vt  = (unsigned short*)alloc((size_t)MT * KVEn * 2);
  float2* cs          = (float2*)alloc((size_t)Sn * 64 * sizeof(float2));
  unsigned short* AO  = xb;   // alias: xb dead after the V projection

  cast_bf16_kernel<<<MT * (En / 4) / 256, 256, 0, stream>>>(x, xb, MT * En / 4);
  tcast_kernel<<<dim3(En / 32, En / 32), dim3(32, 32), 0, stream>>>(Wq, WqT, En, En);
  tcast_kernel<<<dim3(KVEn / 32, En / 32), dim3(32, 32), 0, stream>>>(Wk, WkT, En, KVEn);
  tcast_kernel<<<dim3(KVEn / 32, En / 32), dim3(32, 32), 0, stream>>>(Wv, WvT, En, KVEn);
  tcast_kernel<<<dim3(En / 32, En / 32), dim3(32, 32), 0, stream>>>(Wo, WoT, En, En);
  rope_table_kernel<<<Sn * 64 / 256, 256, 0, stream>>>(cs);

  gemm_kernel<<<dim3(En / 128, MT / 128), 256, 0, stream>>>(xb, WqT, Ql, MT, En, En, 0);
  gemm_kernel<<<dim3(KVEn / 128, MT / 128), 256, 0, stream>>>(xb, WkT, Kl, MT, KVEn, En, 0);
  gemm_kernel<<<dim3(KVEn / 128, MT / 128), 256, 0, stream>>>(xb, WvT, Vl, MT, KVEn, En, 0);

  const float scl = 0.08838834764831845f * 1.4426950408889634f; // (1/sqrt(128))*log2(e)
  rope_kernel<<<dim3(MT, NH / 4), 256, 0, stream>>>(Ql, cs, NH, scl);
  rope_kernel<<<dim3(MT, NKV / 4), 256, 0, stream>>>(Kl, cs, NKV, 1.0f);
  vtrans_kernel<<<dim3(Dh / 32, Sn / 32, Bn * NKV), dim3(32, 32), 0, stream>>>(Vl, Vt);

  attn_kernel<<<dim3(NH, QT, Bn), 512, 0, stream>>>(Ql, Kl, Vt, AO);

  gemm_kernel<<<dim3(En / 128, MT / 128), 256, 0, stream>>>(AO, WoT, d_out, MT, En, En, 1);
}

// Round 4
// 619.774 us; speedup vs baseline: 2.0190x; 1.4110x over previous
//
#include <hip/hip_runtime.h>
#include <stdint.h>
#include <math.h>

typedef short bf16x8 __attribute__((ext_vector_type(8)));
typedef float f32x4 __attribute__((ext_vector_type(4)));

#if __has_builtin(__builtin_amdgcn_exp2f)
#define EXP2F(x) __builtin_amdgcn_exp2f(x)
#else
#define EXP2F(x) exp2f(x)
#endif

static constexpr int Bn   = 2;
static constexpr int Sn   = 2048;
static constexpr int NH   = 32;
static constexpr int NKV  = 8;
static constexpr int Dh   = 128;
static constexpr int En   = NH * Dh;     // 4096
static constexpr int KVEn = NKV * Dh;    // 1024
static constexpr int QKVE = En + 2 * KVEn; // 6144 fused projection width
static constexpr int MT   = Bn * Sn;     // 4096 tokens
static constexpr int QT   = Sn / 128;    // 16 q-tiles (128 rows each)

__device__ __forceinline__ unsigned short f2bf(float f) {
  unsigned int u = __float_as_uint(f);
  u += 0x7FFFu + ((u >> 16) & 1u);
  return (unsigned short)(u >> 16);
}
__device__ __forceinline__ float bf2f(unsigned short h) {
  return __uint_as_float(((unsigned int)h) << 16);
}

typedef __attribute__((address_space(1))) void* gas_t;
typedef __attribute__((address_space(3))) void* las_t;
// async global->LDS, 16B per lane; lds dest must be wave-base + lane*16 (linear)
__device__ __forceinline__ void gl_lds16(const void* g, void* l) {
  __builtin_amdgcn_global_load_lds((gas_t)(uintptr_t)g, (las_t)(uint32_t)(uintptr_t)l,
                                   16, 0, 0);
}

// ---------------- pre/post passes ----------------

__global__ void cast_bf16_kernel(const float* __restrict__ x,
                                 unsigned short* __restrict__ y, int n4) {
  int i = blockIdx.x * 256 + threadIdx.x;
  if (i >= n4) return;
  float4 v = ((const float4*)x)[i];
  ushort4 o;
  o.x = f2bf(v.x); o.y = f2bf(v.y); o.z = f2bf(v.z); o.w = f2bf(v.w);
  ((ushort4*)y)[i] = o;
}

// W [R][C] f32 -> WT [C][R] bf16 (tiled, coalesced both sides)
__global__ void tcast_kernel(const float* __restrict__ W,
                             unsigned short* __restrict__ WT, int R, int C) {
  __shared__ float t[32][33];
  int tx = threadIdx.x, ty = threadIdx.y;
  int c = blockIdx.x * 32 + tx, r = blockIdx.y * 32 + ty;
  t[ty][tx] = W[(size_t)r * C + c];
  __syncthreads();
  int ro = blockIdx.x * 32 + ty, co = blockIdx.y * 32 + tx;
  WT[(size_t)ro * R + co] = f2bf(t[tx][ty]);
}

__global__ void rope_table_kernel(float2* __restrict__ cs) {
  int i = blockIdx.x * 256 + threadIdx.x;   // i < Sn*64
  int s = i >> 6, d = i & 63;
  float inv = powf(10000.0f, -(float)d * (1.0f / 64.0f));
  float a = (float)s * inv;
  cs[i] = make_float2(cosf(a), sinf(a));
}

// in-place RoPE on [MT][rowstride] starting at column 0 of q; pairs (d, d+64)
__global__ void rope_kernel(unsigned short* __restrict__ q,
                            const float2* __restrict__ cs, int rowstride, float scl) {
  int row = blockIdx.x;
  int s = row & (Sn - 1);
  int hl = threadIdx.x >> 6, d = threadIdx.x & 63;
  int h = blockIdx.y * 4 + hl;
  size_t base = (size_t)row * rowstride + (size_t)h * Dh + d;
  float2 c = cs[s * 64 + d];
  float x0 = bf2f(q[base]), x1 = bf2f(q[base + 64]);
  q[base]      = f2bf((x0 * c.x - x1 * c.y) * scl);
  q[base + 64] = f2bf((x1 * c.x + x0 * c.y) * scl);
}

// V (strided rows) -> Vt [B][KV][D][S]  (d-major so PV B-frags are k-contiguous)
__global__ void vtrans_kernel(const unsigned short* __restrict__ V, int rowstride,
                              unsigned short* __restrict__ Vt) {
  __shared__ unsigned short t[32][33];
  int bk = blockIdx.z;                 // b*NKV+kv
  int b = bk >> 3, kv = bk & 7;
  int d = blockIdx.x * 32 + threadIdx.x;
  int s = blockIdx.y * 32 + threadIdx.y;
  t[threadIdx.y][threadIdx.x] = V[(size_t)(b * Sn + s) * rowstride + kv * Dh + d];
  __syncthreads();
  int dd = blockIdx.x * 32 + threadIdx.y;
  int so = blockIdx.y * 32 + threadIdx.x;
  Vt[((size_t)bk * Dh + dd) * Sn + so] = t[threadIdx.x][threadIdx.y];
}

// ---------------- GEMM 256x256 8-phase (T2+T3+T4+T5) ----------------
// A[M,K] bf16, BT[N,K] bf16 -> C[M,N]. 512 thr = 8 waves (2M x 4N), BK=64,
// per-wave out 128x64 (acc[8][4]). LDS 128 KiB: [2 buf][A0,A1,B0,B1][128][64],
// rows XOR-swizzled ((row&7)<<4 on byte col, applied on global src + ds_read).
// 2-deep tile prefetch, counted vmcnt(8) (= 1 K-tile in flight), raw barriers.

__global__ __launch_bounds__(512, 2) void gemm256_kernel(
    const unsigned short* __restrict__ A, const unsigned short* __restrict__ BT,
    void* __restrict__ Cout, int M, int N, int K, int out_f32) {
  __shared__ unsigned short lds[2][4][128 * 64];
  const int tid = threadIdx.x;
  const int lane = tid & 63, wave = tid >> 6;
  const int r15 = lane & 15, kg = lane >> 4;
  const int wm = wave >> 2, wn = wave & 3;
  const int m0 = blockIdx.y * 256, n0 = blockIdx.x * 256;
  const char* Ab = (const char*)A;
  const char* Bb = (const char*)BT;
  const int KT = K >> 6;               // K-tiles of 64 (requires KT >= 2)

  f32x4 acc[8][4] = {};

  auto stage = [&](int ktile, int buf) {   // 8 gl_lds16 per thread
    int k0 = ktile * 64;
#pragma unroll
    for (int half = 0; half < 2; ++half)
#pragma unroll
      for (int ld = 0; ld < 2; ++ld) {
        int f = (ld * 512 + tid) * 16;     // [0,16384) bytes in half-tile
        int row = f >> 7, cb = f & 127;
        int scb = cb ^ ((row & 7) << 4);   // inverse-swizzled global source
        gl_lds16(Ab + ((size_t)(m0 + half * 128 + row) * K + k0) * 2 + scb,
                 (char*)lds[buf][half] + f);
        gl_lds16(Bb + ((size_t)(n0 + half * 128 + row) * K + k0) * 2 + scb,
                 (char*)lds[buf][2 + half] + f);
      }
  };

  stage(0, 0);
  stage(1, 1);
  asm volatile("s_waitcnt vmcnt(8)" ::: "memory");   // tile 0 landed
  __builtin_amdgcn_sched_barrier(0);
  __builtin_amdgcn_s_barrier();
  __builtin_amdgcn_sched_barrier(0);

  for (int kt = 0; kt < KT; ++kt) {
    const int cur = kt & 1;
    const char* Abase = (const char*)lds[cur][wm];
    const char* Bbase = (const char*)lds[cur][2 + (wn >> 1)];
    const int brow0 = (wn & 1) * 64;

    // 4 phases: (ks,mh) with B-frags read once per ks, 16 MFMA per phase
#pragma unroll
    for (int ks = 0; ks < 2; ++ks) {
      bf16x8 bfr[4];
#pragma unroll
      for (int nf = 0; nf < 4; ++nf) {
        int br = brow0 + nf * 16 + r15;
        bfr[nf] = *(const bf16x8*)(Bbase + br * 128 +
                                   ((ks * 64 + kg * 16) ^ ((br & 7) << 4)));
      }
#pragma unroll
      for (int mh = 0; mh < 2; ++mh) {
        bf16x8 afr[4];
#pragma unroll
        for (int mf = 0; mf < 4; ++mf) {
          int ar = mh * 64 + mf * 16 + r15;
          afr[mf] = *(const bf16x8*)(Abase + ar * 128 +
                                     ((ks * 64 + kg * 16) ^ ((ar & 7) << 4)));
        }
        __builtin_amdgcn_s_setprio(1);
#pragma unroll
        for (int mf = 0; mf < 4; ++mf)
#pragma unroll
          for (int nf = 0; nf < 4; ++nf)
            acc[mh * 4 + mf][nf] = __builtin_amdgcn_mfma_f32_16x16x32_bf16(
                afr[mf], bfr[nf], acc[mh * 4 + mf][nf], 0, 0, 0);
        __builtin_amdgcn_s_setprio(0);
      }
    }

    __builtin_amdgcn_sched_barrier(0);
    __builtin_amdgcn_s_barrier();          // all waves done reading buf[cur]
    __builtin_amdgcn_sched_barrier(0);
    if (kt + 2 < KT) {
      stage(kt + 2, cur);                  // overwrite just-freed buffer
      asm volatile("s_waitcnt vmcnt(8)" ::: "memory");  // tile kt+1 landed
    } else {
      asm volatile("s_waitcnt vmcnt(0)" ::: "memory");  // drain tail
    }
    __builtin_amdgcn_sched_barrier(0);
    __builtin_amdgcn_s_barrier();          // buf[cur^1] visible to all
    __builtin_amdgcn_sched_barrier(0);
  }

#pragma unroll
  for (int mh = 0; mh < 2; ++mh)
#pragma unroll
    for (int mf = 0; mf < 4; ++mf)
#pragma unroll
      for (int nf = 0; nf < 4; ++nf)
#pragma unroll
        for (int t = 0; t < 4; ++t) {
          int row = m0 + wm * 128 + mh * 64 + mf * 16 + kg * 4 + t;
          int col = n0 + wn * 64 + nf * 16 + r15;
          if (out_f32)
            ((float*)Cout)[(size_t)row * N + col] = acc[mh * 4 + mf][nf][t];
          else
            ((unsigned short*)Cout)[(size_t)row * N + col] = f2bf(acc[mh * 4 + mf][nf][t]);
        }
}

// ---------------- flash attention (causal, GQA) ----------------
// 512 threads = 8 waves x 16 q-rows => 128 q-rows/block sharing one staged
// K/V tile (KVBLK=64). Double-buffered prefetch, one barrier per k-tile.
// Longest blocks dispatched first. Q pre-scaled by (1/sqrt(D))*log2(e).
// Q/K live in the fused QKV buffer: row stride QKVE elements.

__device__ __forceinline__ void sm_update(f32x4 sc[4], f32x4 o[8],
                                          float mrow[4], float lrow[4],
                                          bool diag, int qrow0, int kt,
                                          int r15, int kg, char* Pw) {
  if (diag) {
#pragma unroll
    for (int kf = 0; kf < 4; ++kf) {
      int kvg = kt * 64 + kf * 16 + r15;
#pragma unroll
      for (int t = 0; t < 4; ++t)
        if (kvg > qrow0 + kg * 4 + t) sc[kf][t] = -1e30f;
    }
  }
  float mx[4], sm[4];
#pragma unroll
  for (int t = 0; t < 4; ++t) {
    float v = fmaxf(fmaxf(sc[0][t], sc[1][t]), fmaxf(sc[2][t], sc[3][t]));
#pragma unroll
    for (int off = 1; off < 16; off <<= 1) v = fmaxf(v, __shfl_xor(v, off, 16));
    mx[t] = fmaxf(mrow[t], v);
    sm[t] = EXP2F(mrow[t] - mx[t]);
    mrow[t] = mx[t];
  }
#pragma unroll
  for (int kf = 0; kf < 4; ++kf)
#pragma unroll
    for (int t = 0; t < 4; ++t) sc[kf][t] = EXP2F(sc[kf][t] - mx[t]);
#pragma unroll
  for (int t = 0; t < 4; ++t) {
    float v = sc[0][t] + sc[1][t] + sc[2][t] + sc[3][t];
#pragma unroll
    for (int off = 1; off < 16; off <<= 1) v += __shfl_xor(v, off, 16);
    lrow[t] = lrow[t] * sm[t] + v;
  }
#pragma unroll
  for (int nf = 0; nf < 8; ++nf)
#pragma unroll
    for (int t = 0; t < 4; ++t) o[nf][t] *= sm[t];
  // P (C-layout) -> per-wave LDS (A-layout source), swizzled
#pragma unroll
  for (int kf = 0; kf < 4; ++kf)
#pragma unroll
    for (int t = 0; t < 4; ++t) {
      int r = kg * 4 + t, c = kf * 16 + r15;
      *(unsigned short*)(Pw + r * 128 + ((c * 2) ^ ((r & 7) << 4))) = f2bf(sc[kf][t]);
    }
}

__global__ __launch_bounds__(512, 4) void attn_kernel(
    const unsigned short* __restrict__ Q, const unsigned short* __restrict__ Kl,
    const unsigned short* __restrict__ Vt, unsigned short* __restrict__ AO) {
  __shared__ unsigned short Ks[2][64 * 128];   // [buf][kv][d], rows XOR-swizzled
  __shared__ unsigned short Vs[2][128 * 64];   // [buf][d][kv], rows XOR-swizzled
  __shared__ unsigned short Ps[8][16 * 64];    // per-wave P, swizzled
  const int tid = threadIdx.x, lane = tid & 63, wave = tid >> 6;
  const int h = blockIdx.x, b = blockIdx.z;
  const int qt = (QT - 1) - blockIdx.y;        // longest-first dispatch
  const int kvh = h >> 2;                      // G = 4
  const int r15 = lane & 15, kg = lane >> 4;
  const int qrow0 = qt * 128 + wave * 16;
  const int kmax = 2 * qt + 2;

  bf16x8 qf[4];
#pragma unroll
  for (int db = 0; db < 4; ++db)
    qf[db] = *(const bf16x8*)&Q[(size_t)(b * Sn + qrow0 + r15) * QKVE +
                                h * Dh + db * 32 + kg * 8];

  f32x4 o[8] = {};
  float mrow[4] = {-1e30f, -1e30f, -1e30f, -1e30f};
  float lrow[4] = {0.f, 0.f, 0.f, 0.f};

  const char* Kbase = (const char*)Kl + (size_t)(b * Sn) * (QKVE * 2) + kvh * 256;
  const char* Vbase = (const char*)Vt + (size_t)((b * NKV + kvh) * Dh) * (Sn * 2);

  auto stage = [&](int kt, int bi) {
#pragma unroll
    for (int c = 0; c < 2; ++c) {
      int f = (c * 512 + tid) * 16;
      int row = f >> 8, cb = f & 255;
      gl_lds16(Kbase + (size_t)(kt * 64 + row) * (QKVE * 2) + (cb ^ ((row & 7) << 4)),
               (char*)Ks[bi] + f);
    }
#pragma unroll
    for (int c = 0; c < 2; ++c) {
      int f = (c * 512 + tid) * 16;
      int row = f >> 7, cb = f & 127;
      gl_lds16(Vbase + (size_t)row * (Sn * 2) + kt * 128 + (cb ^ ((row & 7) << 4)),
               (char*)Vs[bi] + f);
    }
  };

  stage(0, 0);
  __syncthreads();

  for (int kt = 0; kt < kmax; ++kt) {
    const int cur = kt & 1;
    if (kt + 1 < kmax) stage(kt + 1, cur ^ 1);   // prefetch overlaps compute
    // skip tiles fully above the diagonal for this wave's strip (wave-uniform)
    if (kt * 64 <= qrow0 + 15) {
      const char* Kc = (const char*)Ks[cur];
      const char* Vc = (const char*)Vs[cur];
      f32x4 sc[4] = {};
      __builtin_amdgcn_s_setprio(1);
#pragma unroll
      for (int db = 0; db < 4; ++db) {
#pragma unroll
        for (int kf = 0; kf < 4; ++kf) {
          int krow = kf * 16 + r15;
          int cb = (db * 32 + kg * 8) * 2;
          bf16x8 kb = *(const bf16x8*)(Kc + krow * 256 + (cb ^ ((krow & 7) << 4)));
          sc[kf] = __builtin_amdgcn_mfma_f32_16x16x32_bf16(qf[db], kb, sc[kf], 0, 0, 0);
        }
      }
      __builtin_amdgcn_s_setprio(0);

      char* Pw = (char*)Ps[wave];
      bool diag = (kt * 64 + 63) > qrow0;        // tile touches the diagonal
      sm_update(sc, o, mrow, lrow, diag, qrow0, kt, r15, kg, Pw);

      __builtin_amdgcn_s_setprio(1);
#pragma unroll
      for (int ks = 0; ks < 2; ++ks) {
        bf16x8 pa = *(const bf16x8*)(Pw + r15 * 128 + ((kg * 16 + ks * 64) ^ ((r15 & 7) << 4)));
#pragma unroll
        for (int nf = 0; nf < 8; ++nf) {
          int vrow = nf * 16 + r15;
          int cb = (ks * 32 + kg * 8) * 2;
          bf16x8 vb = *(const bf16x8*)(Vc + vrow * 128 + (cb ^ ((vrow & 7) << 4)));
          o[nf] = __builtin_amdgcn_mfma_f32_16x16x32_bf16(pa, vb, o[nf], 0, 0, 0);
        }
      }
      __builtin_amdgcn_s_setprio(0);
    }
    __syncthreads();
  }

  float rinv[4];
#pragma unroll
  for (int t = 0; t < 4; ++t) rinv[t] = 1.0f / lrow[t];
#pragma unroll
  for (int nf = 0; nf < 8; ++nf)
#pragma unroll
    for (int t = 0; t < 4; ++t) {
      int srow = qrow0 + kg * 4 + t;
      AO[(size_t)(b * Sn + srow) * En + h * Dh + nf * 16 + r15] = f2bf(o[nf][t] * rinv[t]);
    }
}

// ---------------- launch ----------------

extern "C" void kernel_launch(void* const* d_in, const int* in_sizes, int n_in,
                              void* d_out, int out_size, void* d_ws, size_t ws_size,
                              hipStream_t stream) {
  const float* x  = (const float*)d_in[0];
  const float* Wq = (const float*)d_in[1];
  const float* Wk = (const float*)d_in[2];
  const float* Wv = (const float*)d_in[3];
  const float* Wo = (const float*)d_in[4];

  char* ws = (char*)d_ws;
  size_t off = 0;
  auto alloc = [&](size_t bytes) -> char* {
    char* p = ws + off;
    off += (bytes + 255) & ~(size_t)255;
    return p;
  };
  unsigned short* xb   = (unsigned short*)alloc((size_t)MT * En * 2);
  unsigned short* Wqkv = (unsigned short*)alloc((size_t)QKVE * En * 2); // rows: WqT|WkT|WvT
  unsigned short* WoT  = (unsigned short*)alloc((size_t)En * En * 2);
  unsigned short* Cqkv = (unsigned short*)alloc((size_t)MT * QKVE * 2); // [tok][Q|K|V]
  unsigned short* Vt   = (unsigned short*)alloc((size_t)MT * KVEn * 2);
  float2* cs           = (float2*)alloc((size_t)Sn * 64 * sizeof(float2));
  unsigned short* AO   = xb;   // alias: xb dead after the QKV projection

  cast_bf16_kernel<<<MT * (En / 4) / 256, 256, 0, stream>>>(x, xb, MT * En / 4);
  tcast_kernel<<<dim3(En / 32, En / 32), dim3(32, 32), 0, stream>>>(Wq, Wqkv, En, En);
  tcast_kernel<<<dim3(KVEn / 32, En / 32), dim3(32, 32), 0, stream>>>(
      Wk, Wqkv + (size_t)En * En, En, KVEn);
  tcast_kernel<<<dim3(KVEn / 32, En / 32), dim3(32, 32), 0, stream>>>(
      Wv, Wqkv + (size_t)(En + KVEn) * En, En, KVEn);
  tcast_kernel<<<dim3(En / 32, En / 32), dim3(32, 32), 0, stream>>>(Wo, WoT, En, En);
  rope_table_kernel<<<Sn * 64 / 256, 256, 0, stream>>>(cs);

  // fused QKV projection: [MT,4096] x [6144,4096]^T -> [MT,6144]
  gemm256_kernel<<<dim3(QKVE / 256, MT / 256), 512, 0, stream>>>(
      xb, Wqkv, Cqkv, MT, QKVE, En, 0);

  const float scl = 0.08838834764831845f * 1.4426950408889634f; // (1/sqrt(128))*log2(e)
  rope_kernel<<<dim3(MT, NH / 4), 256, 0, stream>>>(Cqkv, cs, QKVE, scl);
  rope_kernel<<<dim3(MT, NKV / 4), 256, 0, stream>>>(Cqkv + En, cs, QKVE, 1.0f);
  vtrans_kernel<<<dim3(Dh / 32, Sn / 32, Bn * NKV), dim3(32, 32), 0, stream>>>(
      Cqkv + En + KVEn, QKVE, Vt);

  attn_kernel<<<dim3(NH, QT, Bn), 512, 0, stream>>>(Cqkv, Cqkv + En, Vt, AO);

  gemm256_kernel<<<dim3(En / 256, MT / 256), 512, 0, stream>>>(
      AO, WoT, d_out, MT, En, En, 1);
}

// Round 5
// 617.867 us; speedup vs baseline: 2.0252x; 1.0031x over previous
//
#include <hip/hip_runtime.h>
#include <stdint.h>
#include <math.h>

typedef short bf16x8 __attribute__((ext_vector_type(8)));
typedef float f32x4 __attribute__((ext_vector_type(4)));

#if __has_builtin(__builtin_amdgcn_exp2f)
#define EXP2F(x) __builtin_amdgcn_exp2f(x)
#else
#define EXP2F(x) exp2f(x)
#endif

static constexpr int Bn   = 2;
static constexpr int Sn   = 2048;
static constexpr int NH   = 32;
static constexpr int NKV  = 8;
static constexpr int Dh   = 128;
static constexpr int En   = NH * Dh;     // 4096
static constexpr int KVEn = NKV * Dh;    // 1024
static constexpr int QKVE = En + 2 * KVEn; // 6144 fused projection width
static constexpr int MT   = Bn * Sn;     // 4096 tokens
static constexpr int QT   = Sn / 128;    // 16 q-tiles (128 rows each)

__device__ __forceinline__ unsigned short f2bf(float f) {
  unsigned int u = __float_as_uint(f);
  u += 0x7FFFu + ((u >> 16) & 1u);
  return (unsigned short)(u >> 16);
}
__device__ __forceinline__ float bf2f(unsigned short h) {
  return __uint_as_float(((unsigned int)h) << 16);
}

typedef __attribute__((address_space(1))) void* gas_t;
typedef __attribute__((address_space(3))) void* las_t;
// async global->LDS, 16B per lane; lds dest must be wave-base + lane*16 (linear)
__device__ __forceinline__ void gl_lds16(const void* g, void* l) {
  __builtin_amdgcn_global_load_lds((gas_t)(uintptr_t)g, (las_t)(uint32_t)(uintptr_t)l,
                                   16, 0, 0);
}

#define VMW(n)  asm volatile("s_waitcnt vmcnt(" #n ")" ::: "memory")
#define LGKM0   asm volatile("s_waitcnt lgkmcnt(0)" ::: "memory")
#define SCHEDB  __builtin_amdgcn_sched_barrier(0)
#define BAR     __builtin_amdgcn_s_barrier()

// ---------------- pre/post passes ----------------

__global__ void cast_bf16_kernel(const float* __restrict__ x,
                                 unsigned short* __restrict__ y, int n4) {
  int i = blockIdx.x * 256 + threadIdx.x;
  if (i >= n4) return;
  float4 v = ((const float4*)x)[i];
  ushort4 o;
  o.x = f2bf(v.x); o.y = f2bf(v.y); o.z = f2bf(v.z); o.w = f2bf(v.w);
  ((ushort4*)y)[i] = o;
}

// W [R][C] f32 -> WT [C][R] bf16 (tiled, coalesced both sides)
__global__ void tcast_kernel(const float* __restrict__ W,
                             unsigned short* __restrict__ WT, int R, int C) {
  __shared__ float t[32][33];
  int tx = threadIdx.x, ty = threadIdx.y;
  int c = blockIdx.x * 32 + tx, r = blockIdx.y * 32 + ty;
  t[ty][tx] = W[(size_t)r * C + c];
  __syncthreads();
  int ro = blockIdx.x * 32 + ty, co = blockIdx.y * 32 + tx;
  WT[(size_t)ro * R + co] = f2bf(t[tx][ty]);
}

__global__ void rope_table_kernel(float2* __restrict__ cs) {
  int i = blockIdx.x * 256 + threadIdx.x;   // i < Sn*64
  int s = i >> 6, d = i & 63;
  float inv = powf(10000.0f, -(float)d * (1.0f / 64.0f));
  float a = (float)s * inv;
  cs[i] = make_float2(cosf(a), sinf(a));
}

// in-place RoPE on [MT][rowstride] starting at column 0 of q; pairs (d, d+64)
__global__ void rope_kernel(unsigned short* __restrict__ q,
                            const float2* __restrict__ cs, int rowstride, float scl) {
  int row = blockIdx.x;
  int s = row & (Sn - 1);
  int hl = threadIdx.x >> 6, d = threadIdx.x & 63;
  int h = blockIdx.y * 4 + hl;
  size_t base = (size_t)row * rowstride + (size_t)h * Dh + d;
  float2 c = cs[s * 64 + d];
  float x0 = bf2f(q[base]), x1 = bf2f(q[base + 64]);
  q[base]      = f2bf((x0 * c.x - x1 * c.y) * scl);
  q[base + 64] = f2bf((x1 * c.x + x0 * c.y) * scl);
}

// V (strided rows) -> Vt [B][KV][D][S]  (d-major so PV B-frags are k-contiguous)
__global__ void vtrans_kernel(const unsigned short* __restrict__ V, int rowstride,
                              unsigned short* __restrict__ Vt) {
  __shared__ unsigned short t[32][33];
  int bk = blockIdx.z;                 // b*NKV+kv
  int b = bk >> 3, kv = bk & 7;
  int d = blockIdx.x * 32 + threadIdx.x;
  int s = blockIdx.y * 32 + threadIdx.y;
  t[threadIdx.y][threadIdx.x] = V[(size_t)(b * Sn + s) * rowstride + kv * Dh + d];
  __syncthreads();
  int dd = blockIdx.x * 32 + threadIdx.y;
  int so = blockIdx.y * 32 + threadIdx.x;
  Vt[((size_t)bk * Dh + dd) * Sn + so] = t[threadIdx.x][threadIdx.y];
}

// ---------------- GEMM 256x256, true 8-phase (T2+T3+T4+T5) ----------------
// A[M,K] bf16, BT[N,K] bf16 -> C[M,N]. 512 thr = 8 waves. BK=64.
// Phase = block-level C-quadrant 128x128 (all 8 waves remapped into it, 2x4,
// 64x32 piece each, 16 MFMA). 8 phases process 2 K-tiles; each phase stages
// exactly one half-tile (128x64, 2 gl_lds/thread). buf0 = even K-tiles,
// buf1 = odd. Stage order: A1(k+1),B1(k+1),A0(k+2),B0(k+2),A1(k+2),B1(k+2),
// A0(k+3),B0(k+3). Counted vmcnt {6,10,-,8,6,10,-,8} derived from slot/landing
// proof; never drained to 0 in the main loop. Rows XOR-swizzled (row&7)<<4,
// same involution on global source and ds_read. KT must be even, >= 4.

__global__ __launch_bounds__(512, 2) void gemm256_kernel(
    const unsigned short* __restrict__ A, const unsigned short* __restrict__ BT,
    void* __restrict__ Cout, int M, int N, int K, int out_f32) {
  __shared__ unsigned short lds[2][4][128 * 64];  // [buf][A0,A1,B0,B1]
  const int tid = threadIdx.x;
  const int lane = tid & 63, wave = tid >> 6;
  const int r15 = lane & 15, kg = lane >> 4;
  const int wr = wave >> 2, wc = wave & 3;        // wave pos within quadrant
  const int m0 = blockIdx.y * 256, n0 = blockIdx.x * 256;
  const char* Ab = (const char*)A;
  const char* Bb = (const char*)BT;
  const int KT = K >> 6;

  f32x4 acc[2][2][4][2] = {};   // [mh][nh][mf][nf]
  bf16x8 ar[4][2];              // current quadrant's A frags [mf][ks]
  bf16x8 br[2][2][2];           // persistent B frags [nh][nf][ks]

#define STAGE_H(SRC, ROW0, KT_, SLOT)                                         \
  do {                                                                        \
    _Pragma("unroll") for (int ld = 0; ld < 2; ++ld) {                        \
      int _f = (ld * 512 + tid) * 16;                                         \
      int _row = _f >> 7, _cb = _f & 127;                                     \
      gl_lds16(SRC + ((size_t)((ROW0) + _row) * K + (KT_) * 64) * 2 +         \
                   (_cb ^ ((_row & 7) << 4)),                                 \
               (char*)(SLOT) + _f);                                           \
    }                                                                         \
  } while (0)

#define GPHASE(MH, NH, BUF, DO_LDA, DO_LDB, STAGE_STMT, WAIT_STMT)            \
  do {                                                                        \
    if (DO_LDA) {                                                             \
      const char* _as = (const char*)lds[BUF][MH];                            \
      _Pragma("unroll") for (int mf = 0; mf < 4; ++mf) {                      \
        int _r = wr * 64 + mf * 16 + r15;                                     \
        int _sw = (_r & 7) << 4;                                              \
        ar[mf][0] = *(const bf16x8*)(_as + _r * 128 + ((kg * 16) ^ _sw));     \
        ar[mf][1] = *(const bf16x8*)(_as + _r * 128 + ((64 + kg * 16) ^ _sw));\
      }                                                                       \
    }                                                                         \
    if (DO_LDB) {                                                             \
      const char* _bs = (const char*)lds[BUF][2 + NH];                        \
      _Pragma("unroll") for (int nf = 0; nf < 2; ++nf) {                      \
        int _r = wc * 32 + nf * 16 + r15;                                     \
        int _sw = (_r & 7) << 4;                                              \
        br[NH][nf][0] =                                                       \
            *(const bf16x8*)(_bs + _r * 128 + ((kg * 16) ^ _sw));             \
        br[NH][nf][1] =                                                       \
            *(const bf16x8*)(_bs + _r * 128 + ((64 + kg * 16) ^ _sw));        \
      }                                                                       \
    }                                                                         \
    STAGE_STMT;                                                               \
    BAR;                                                                      \
    if ((DO_LDA) || (DO_LDB)) { LGKM0; }                                      \
    SCHEDB;                                                                   \
    __builtin_amdgcn_s_setprio(1);                                            \
    _Pragma("unroll") for (int mf = 0; mf < 4; ++mf)                          \
      _Pragma("unroll") for (int nf = 0; nf < 2; ++nf) {                      \
        acc[MH][NH][mf][nf] = __builtin_amdgcn_mfma_f32_16x16x32_bf16(        \
            ar[mf][0], br[NH][nf][0], acc[MH][NH][mf][nf], 0, 0, 0);          \
        acc[MH][NH][mf][nf] = __builtin_amdgcn_mfma_f32_16x16x32_bf16(        \
            ar[mf][1], br[NH][nf][1], acc[MH][NH][mf][nf], 0, 0, 0);          \
      }                                                                       \
    __builtin_amdgcn_s_setprio(0);                                            \
    SCHEDB;                                                                   \
    WAIT_STMT;                                                                \
    BAR;                                                                      \
    SCHEDB;                                                                   \
  } while (0)

  // prologue: halves in steady-state order A0(0),B0(0),A1(0),B1(0),A0(1),B0(1)
  STAGE_H(Ab, m0,       0, lds[0][0]);
  STAGE_H(Bb, n0,       0, lds[0][2]);
  STAGE_H(Ab, m0 + 128, 0, lds[0][1]);
  STAGE_H(Bb, n0 + 128, 0, lds[0][3]);
  STAGE_H(Ab, m0,       1, lds[1][0]);
  STAGE_H(Bb, n0,       1, lds[1][2]);
  VMW(8);
  SCHEDB;
  BAR;
  SCHEDB;

  for (int k = 0; k + 2 < KT; k += 2) {
    GPHASE(0, 0, 0, true,  true,  STAGE_H(Ab, m0 + 128, k + 1, lds[1][1]), VMW(6));
    GPHASE(0, 1, 0, false, true,  STAGE_H(Bb, n0 + 128, k + 1, lds[1][3]), VMW(10));
    GPHASE(1, 0, 0, true,  false, STAGE_H(Ab, m0,       k + 2, lds[0][0]), (void)0);
    GPHASE(1, 1, 0, false, false, STAGE_H(Bb, n0,       k + 2, lds[0][2]), VMW(8));
    GPHASE(0, 0, 1, true,  true,  STAGE_H(Ab, m0 + 128, k + 2, lds[0][1]), VMW(6));
    GPHASE(0, 1, 1, false, true,  STAGE_H(Bb, n0 + 128, k + 2, lds[0][3]), VMW(10));
    GPHASE(1, 0, 1, true,  false, STAGE_H(Ab, m0,       k + 3, lds[1][0]), (void)0);
    GPHASE(1, 1, 1, false, false, STAGE_H(Bb, n0,       k + 3, lds[1][2]), VMW(8));
  }
  // peeled final iteration (k = KT-2): stage only A1/B1 of KT-1, drain once
  GPHASE(0, 0, 0, true,  true,  STAGE_H(Ab, m0 + 128, KT - 1, lds[1][1]), VMW(6));
  GPHASE(0, 1, 0, false, true,  STAGE_H(Bb, n0 + 128, KT - 1, lds[1][3]), VMW(10));
  GPHASE(1, 0, 0, true,  false, (void)0, (void)0);
  GPHASE(1, 1, 0, false, false, (void)0, VMW(0));
  GPHASE(0, 0, 1, true,  true,  (void)0, (void)0);
  GPHASE(0, 1, 1, false, true,  (void)0, (void)0);
  GPHASE(1, 0, 1, true,  false, (void)0, (void)0);
  GPHASE(1, 1, 1, false, false, (void)0, (void)0);

#undef GPHASE
#undef STAGE_H

#pragma unroll
  for (int mh = 0; mh < 2; ++mh)
#pragma unroll
    for (int nh = 0; nh < 2; ++nh)
#pragma unroll
      for (int mf = 0; mf < 4; ++mf)
#pragma unroll
        for (int nf = 0; nf < 2; ++nf)
#pragma unroll
          for (int t = 0; t < 4; ++t) {
            int row = m0 + mh * 128 + wr * 64 + mf * 16 + kg * 4 + t;
            int col = n0 + nh * 128 + wc * 32 + nf * 16 + r15;
            if (out_f32)
              ((float*)Cout)[(size_t)row * N + col] = acc[mh][nh][mf][nf][t];
            else
              ((unsigned short*)Cout)[(size_t)row * N + col] =
                  f2bf(acc[mh][nh][mf][nf][t]);
          }
}

// ---------------- flash attention (causal, GQA) ----------------
// 512 threads = 8 waves x 16 q-rows => 128 q-rows/block sharing one staged
// K/V tile (KVBLK=64). Double-buffered prefetch, one barrier per k-tile.
// Longest blocks dispatched first. Q pre-scaled by (1/sqrt(D))*log2(e).
// Q/K live in the fused QKV buffer: row stride QKVE elements.

__device__ __forceinline__ void sm_update(f32x4 sc[4], f32x4 o[8],
                                          float mrow[4], float lrow[4],
                                          bool diag, int qrow0, int kt,
                                          int r15, int kg, char* Pw) {
  if (diag) {
#pragma unroll
    for (int kf = 0; kf < 4; ++kf) {
      int kvg = kt * 64 + kf * 16 + r15;
#pragma unroll
      for (int t = 0; t < 4; ++t)
        if (kvg > qrow0 + kg * 4 + t) sc[kf][t] = -1e30f;
    }
  }
  float mx[4], sm[4];
#pragma unroll
  for (int t = 0; t < 4; ++t) {
    float v = fmaxf(fmaxf(sc[0][t], sc[1][t]), fmaxf(sc[2][t], sc[3][t]));
#pragma unroll
    for (int off = 1; off < 16; off <<= 1) v = fmaxf(v, __shfl_xor(v, off, 16));
    mx[t] = fmaxf(mrow[t], v);
    sm[t] = EXP2F(mrow[t] - mx[t]);
    mrow[t] = mx[t];
  }
#pragma unroll
  for (int kf = 0; kf < 4; ++kf)
#pragma unroll
    for (int t = 0; t < 4; ++t) sc[kf][t] = EXP2F(sc[kf][t] - mx[t]);
#pragma unroll
  for (int t = 0; t < 4; ++t) {
    float v = sc[0][t] + sc[1][t] + sc[2][t] + sc[3][t];
#pragma unroll
    for (int off = 1; off < 16; off <<= 1) v += __shfl_xor(v, off, 16);
    lrow[t] = lrow[t] * sm[t] + v;
  }
#pragma unroll
  for (int nf = 0; nf < 8; ++nf)
#pragma unroll
    for (int t = 0; t < 4; ++t) o[nf][t] *= sm[t];
  // P (C-layout) -> per-wave LDS (A-layout source), swizzled
#pragma unroll
  for (int kf = 0; kf < 4; ++kf)
#pragma unroll
    for (int t = 0; t < 4; ++t) {
      int r = kg * 4 + t, c = kf * 16 + r15;
      *(unsigned short*)(Pw + r * 128 + ((c * 2) ^ ((r & 7) << 4))) = f2bf(sc[kf][t]);
    }
}

__global__ __launch_bounds__(512, 4) void attn_kernel(
    const unsigned short* __restrict__ Q, const unsigned short* __restrict__ Kl,
    const unsigned short* __restrict__ Vt, unsigned short* __restrict__ AO) {
  __shared__ unsigned short Ks[2][64 * 128];   // [buf][kv][d], rows XOR-swizzled
  __shared__ unsigned short Vs[2][128 * 64];   // [buf][d][kv], rows XOR-swizzled
  __shared__ unsigned short Ps[8][16 * 64];    // per-wave P, swizzled
  const int tid = threadIdx.x, lane = tid & 63, wave = tid >> 6;
  const int h = blockIdx.x, b = blockIdx.z;
  const int qt = (QT - 1) - blockIdx.y;        // longest-first dispatch
  const int kvh = h >> 2;                      // G = 4
  const int r15 = lane & 15, kg = lane >> 4;
  const int qrow0 = qt * 128 + wave * 16;
  const int kmax = 2 * qt + 2;

  bf16x8 qf[4];
#pragma unroll
  for (int db = 0; db < 4; ++db)
    qf[db] = *(const bf16x8*)&Q[(size_t)(b * Sn + qrow0 + r15) * QKVE +
                                h * Dh + db * 32 + kg * 8];

  f32x4 o[8] = {};
  float mrow[4] = {-1e30f, -1e30f, -1e30f, -1e30f};
  float lrow[4] = {0.f, 0.f, 0.f, 0.f};

  const char* Kbase = (const char*)Kl + (size_t)(b * Sn) * (QKVE * 2) + kvh * 256;
  const char* Vbase = (const char*)Vt + (size_t)((b * NKV + kvh) * Dh) * (Sn * 2);

  auto stage = [&](int kt, int bi) {
#pragma unroll
    for (int c = 0; c < 2; ++c) {
      int f = (c * 512 + tid) * 16;
      int row = f >> 8, cb = f & 255;
      gl_lds16(Kbase + (size_t)(kt * 64 + row) * (QKVE * 2) + (cb ^ ((row & 7) << 4)),
               (char*)Ks[bi] + f);
    }
#pragma unroll
    for (int c = 0; c < 2; ++c) {
      int f = (c * 512 + tid) * 16;
      int row = f >> 7, cb = f & 127;
      gl_lds16(Vbase + (size_t)row * (Sn * 2) + kt * 128 + (cb ^ ((row & 7) << 4)),
               (char*)Vs[bi] + f);
    }
  };

  stage(0, 0);
  __syncthreads();

  for (int kt = 0; kt < kmax; ++kt) {
    const int cur = kt & 1;
    if (kt + 1 < kmax) stage(kt + 1, cur ^ 1);   // prefetch overlaps compute
    // skip tiles fully above the diagonal for this wave's strip (wave-uniform)
    if (kt * 64 <= qrow0 + 15) {
      const char* Kc = (const char*)Ks[cur];
      const char* Vc = (const char*)Vs[cur];
      f32x4 sc[4] = {};
      __builtin_amdgcn_s_setprio(1);
#pragma unroll
      for (int db = 0; db < 4; ++db) {
#pragma unroll
        for (int kf = 0; kf < 4; ++kf) {
          int krow = kf * 16 + r15;
          int cb = (db * 32 + kg * 8) * 2;
          bf16x8 kb = *(const bf16x8*)(Kc + krow * 256 + (cb ^ ((krow & 7) << 4)));
          sc[kf] = __builtin_amdgcn_mfma_f32_16x16x32_bf16(qf[db], kb, sc[kf], 0, 0, 0);
        }
      }
      __builtin_amdgcn_s_setprio(0);

      char* Pw = (char*)Ps[wave];
      bool diag = (kt * 64 + 63) > qrow0;        // tile touches the diagonal
      sm_update(sc, o, mrow, lrow, diag, qrow0, kt, r15, kg, Pw);

      __builtin_amdgcn_s_setprio(1);
#pragma unroll
      for (int ks = 0; ks < 2; ++ks) {
        bf16x8 pa = *(const bf16x8*)(Pw + r15 * 128 + ((kg * 16 + ks * 64) ^ ((r15 & 7) << 4)));
#pragma unroll
        for (int nf = 0; nf < 8; ++nf) {
          int vrow = nf * 16 + r15;
          int cb = (ks * 32 + kg * 8) * 2;
          bf16x8 vb = *(const bf16x8*)(Vc + vrow * 128 + (cb ^ ((vrow & 7) << 4)));
          o[nf] = __builtin_amdgcn_mfma_f32_16x16x32_bf16(pa, vb, o[nf], 0, 0, 0);
        }
      }
      __builtin_amdgcn_s_setprio(0);
    }
    __syncthreads();
  }

  float rinv[4];
#pragma unroll
  for (int t = 0; t < 4; ++t) rinv[t] = 1.0f / lrow[t];
#pragma unroll
  for (int nf = 0; nf < 8; ++nf)
#pragma unroll
    for (int t = 0; t < 4; ++t) {
      int srow = qrow0 + kg * 4 + t;
      AO[(size_t)(b * Sn + srow) * En + h * Dh + nf * 16 + r15] = f2bf(o[nf][t] * rinv[t]);
    }
}

// ---------------- launch ----------------

extern "C" void kernel_launch(void* const* d_in, const int* in_sizes, int n_in,
                              void* d_out, int out_size, void* d_ws, size_t ws_size,
                              hipStream_t stream) {
  const float* x  = (const float*)d_in[0];
  const float* Wq = (const float*)d_in[1];
  const float* Wk = (const float*)d_in[2];
  const float* Wv = (const float*)d_in[3];
  const float* Wo = (const float*)d_in[4];

  char* ws = (char*)d_ws;
  size_t off = 0;
  auto alloc = [&](size_t bytes) -> char* {
    char* p = ws + off;
    off += (bytes + 255) & ~(size_t)255;
    return p;
  };
  unsigned short* xb   = (unsigned short*)alloc((size_t)MT * En * 2);
  unsigned short* Wqkv = (unsigned short*)alloc((size_t)QKVE * En * 2); // rows: WqT|WkT|WvT
  unsigned short* WoT  = (unsigned short*)alloc((size_t)En * En * 2);
  unsigned short* Cqkv = (unsigned short*)alloc((size_t)MT * QKVE * 2); // [tok][Q|K|V]
  unsigned short* Vt   = (unsigned short*)alloc((size_t)MT * KVEn * 2);
  float2* cs           = (float2*)alloc((size_t)Sn * 64 * sizeof(float2));
  unsigned short* AO   = xb;   // alias: xb dead after the QKV projection

  cast_bf16_kernel<<<MT * (En / 4) / 256, 256, 0, stream>>>(x, xb, MT * En / 4);
  tcast_kernel<<<dim3(En / 32, En / 32), dim3(32, 32), 0, stream>>>(Wq, Wqkv, En, En);
  tcast_kernel<<<dim3(KVEn / 32, En / 32), dim3(32, 32), 0, stream>>>(
      Wk, Wqkv + (size_t)En * En, En, KVEn);
  tcast_kernel<<<dim3(KVEn / 32, En / 32), dim3(32, 32), 0, stream>>>(
      Wv, Wqkv + (size_t)(En + KVEn) * En, En, KVEn);
  tcast_kernel<<<dim3(En / 32, En / 32), dim3(32, 32), 0, stream>>>(Wo, WoT, En, En);
  rope_table_kernel<<<Sn * 64 / 256, 256, 0, stream>>>(cs);

  // fused QKV projection: [MT,4096] x [6144,4096]^T -> [MT,6144]
  gemm256_kernel<<<dim3(QKVE / 256, MT / 256), 512, 0, stream>>>(
      xb, Wqkv, Cqkv, MT, QKVE, En, 0);

  const float scl = 0.08838834764831845f * 1.4426950408889634f; // (1/sqrt(128))*log2(e)
  rope_kernel<<<dim3(MT, NH / 4), 256, 0, stream>>>(Cqkv, cs, QKVE, scl);
  rope_kernel<<<dim3(MT, NKV / 4), 256, 0, stream>>>(Cqkv + En, cs, QKVE, 1.0f);
  vtrans_kernel<<<dim3(Dh / 32, Sn / 32, Bn * NKV), dim3(32, 32), 0, stream>>>(
      Cqkv + En + KVEn, QKVE, Vt);

  attn_kernel<<<dim3(NH, QT, Bn), 512, 0, stream>>>(Cqkv, Cqkv + En, Vt, AO);

  gemm256_kernel<<<dim3(En / 256, MT / 256), 512, 0, stream>>>(
      AO, WoT, d_out, MT, En, En, 1);
}